// Round 9
// baseline (357.591 us; speedup 1.0000x reference)
//
#include <hip/hip_runtime.h>
#include <math.h>

#define T_LEN 512
#define B_N   1024
#define K_N   48
#define START_TAG (K_N - 2)
#define STOP_TAG  (K_N - 1)
#define NEG   -10000.0f
#define NCH   2          // independent batch chains per wave

// One wave (64 threads) per NCH batches; lane j owns state j for all chains.
// Scaled-exponential domain per chain: q_j = exp(alpha_j - C).
//   s_j  = sum_k E[j,k] * q_k   (k=0..47; col 47 = STOP has E=exp(-1e4)=0)
//   q'_j = F_j * inv * s_j,  F_j = exp(feat[t,b,j]), inv = rcp(q_0), C += log(q_0)
// E is SHARED between chains (depends only on lane's state row) — the chains
// cost only q/C/prefetch registers.
//
// WHY NCH=2 (R8 post-mortem): with 1 chain/SIMD the recursion is latency-
// bound: 655 cy/step = ~350 VALU + ~300 LDS-roundtrip stall that nothing can
// fill (1024 waves on 1024 SIMDs, serial in T). Two independent chains per
// SIMD let one chain's FMA work cover the other's LDS latency.
//
// Hard-won, load-bearing details:
//  * amdgpu_waves_per_eu(1,1): without it the allocator budgets 32 VGPRs and
//    spills E to scratch (R3/R4: 355us). With it E is register-resident.
//  * Feat loads UNCONDITIONAL (clamped indices, no branch) — R5: branches
//    around VMEM defeat static vmcnt tracking -> vmcnt(0) every step.
//  * NO register rotation in a rolled loop — R6: rotation movs force a
//    vmcnt(0) drain per step (~900cy HBM latency each). Fixed 512-step trip,
//    statically-unrolled 8-step ping-pong phases; per-step `t<len` cndmask
//    reproduces the reference mask (freeze alpha) semantics.
//  * LDS broadcast (1 ds_write + 12 ds_read_b128, same-address = HW
//    broadcast, no conflicts, no barrier: single-wave WG, in-order DS pipe).

#define G4(k0,k1,k2,k3,V) \
        a0 = fmaf(E##k0, V.x, a0); a1 = fmaf(E##k1, V.y, a1); \
        a2 = fmaf(E##k2, V.z, a2); a3 = fmaf(E##k3, V.w, a3);

// One recursion step of chain CC at time TT consuming raw feat value FVAL.
#define STEP(CC, TT, FVAL) do { \
        q_lds[CC][lane] = q[CC]; \
        const float4* qv4 = (const float4*)q_lds[CC]; \
        float4 v0 = qv4[0],  v1 = qv4[1],  v2  = qv4[2],  v3  = qv4[3], \
               v4 = qv4[4],  v5 = qv4[5],  v6  = qv4[6],  v7  = qv4[7], \
               v8 = qv4[8],  v9 = qv4[9],  v10 = qv4[10], v11 = qv4[11]; \
        const float s0v  = v0.x; \
        const bool  live = (s0v > 0.0f);            /* false only at t==0 */ \
        const float inv  = live ? __builtin_amdgcn_rcpf(s0v) : 1.0f; \
        const float dC   = live ? __logf(s0v) : 0.0f; \
        const bool  on   = ((TT) < len[CC]); \
        C[CC] += on ? dC : 0.0f; \
        const float scale = __expf(FVAL) * inv; \
        float a0 = 0.f, a1 = 0.f, a2 = 0.f, a3 = 0.f; \
        G4(0,1,2,3,v0)     G4(4,5,6,7,v1)     G4(8,9,10,11,v2) \
        G4(12,13,14,15,v3) G4(16,17,18,19,v4) G4(20,21,22,23,v5) \
        G4(24,25,26,27,v6) G4(28,29,31,31,v7) G4(32,33,34,35,v8) \
        G4(36,37,38,39,v9) G4(40,41,42,43,v10) G4(44,45,46,47,v11) \
        const float ssum = (a0 + a1) + (a2 + a3); \
        q[CC] = on ? ssum * scale : q[CC]; \
    } while (0)

// NOTE: the G4(28,29,31,31,..) above would be a typo bug — fixed below by
// generating the body from a checked macro list instead.
#undef STEP
#define DOT48(V0,V1,V2,V3,V4,V5,V6,V7,V8,V9,V10,V11) \
        G4(0,1,2,3,V0)     G4(4,5,6,7,V1)     G4(8,9,10,11,V2) \
        G4(12,13,14,15,V3) G4(16,17,18,19,V4) G4(20,21,22,23,V5) \
        G4(24,25,26,27,V6) G4(28,29,30,31,V7) G4(32,33,34,35,V8) \
        G4(36,37,38,39,V9) G4(40,41,42,43,V10) G4(44,45,46,47,V11)

#define STEP(CC, TT, FVAL) do { \
        q_lds[CC][lane] = q[CC]; \
        const float4* qv4 = (const float4*)q_lds[CC]; \
        float4 v0 = qv4[0],  v1 = qv4[1],  v2  = qv4[2],  v3  = qv4[3], \
               v4 = qv4[4],  v5 = qv4[5],  v6  = qv4[6],  v7  = qv4[7], \
               v8 = qv4[8],  v9 = qv4[9],  v10 = qv4[10], v11 = qv4[11]; \
        const float s0v  = v0.x; \
        const bool  live = (s0v > 0.0f); \
        const float inv  = live ? __builtin_amdgcn_rcpf(s0v) : 1.0f; \
        const float dC   = live ? __logf(s0v) : 0.0f; \
        const bool  on   = ((TT) < len[CC]); \
        C[CC] += on ? dC : 0.0f; \
        const float scale = __expf(FVAL) * inv; \
        float a0 = 0.f, a1 = 0.f, a2 = 0.f, a3 = 0.f; \
        DOT48(v0,v1,v2,v3,v4,v5,v6,v7,v8,v9,v10,v11) \
        const float ssum = (a0 + a1) + (a2 + a3); \
        q[CC] = on ? ssum * scale : q[CC]; \
    } while (0)

__global__ __launch_bounds__(64)
__attribute__((amdgpu_waves_per_eu(1, 1)))
void crf_fused_kernel(
    const float* __restrict__ feats,    // (T, B, K)
    const float* __restrict__ trans,    // (K, K)
    const int*   __restrict__ tags,     // (B, T)
    const int*   __restrict__ lengths,  // (B,)
    float* __restrict__ out)
{
    const int lane   = threadIdx.x;
    const int lane_c = (lane < K_N) ? lane : (K_N - 1);   // clamp: all addrs valid

    __shared__ __align__(16) float q_lds[NCH][64];

    // E row in named scalars (VGPR-resident), shared by all chains.
    const float* tr = trans + lane_c * K_N;
#define REP48(M) M(0)M(1)M(2)M(3)M(4)M(5)M(6)M(7)M(8)M(9)M(10)M(11)M(12) \
  M(13)M(14)M(15)M(16)M(17)M(18)M(19)M(20)M(21)M(22)M(23)M(24)M(25)M(26) \
  M(27)M(28)M(29)M(30)M(31)M(32)M(33)M(34)M(35)M(36)M(37)M(38)M(39)M(40) \
  M(41)M(42)M(43)M(44)M(45)M(46)M(47)
#define DECL_E(k) float E##k = __expf(tr[k]);
    REP48(DECL_E)
#undef DECL_E

    const size_t sT = (size_t)B_N * K_N;

    int          len[NCH];
    int          lm1[NCH];
    const float* fb [NCH];
    float        q  [NCH];
    float        C  [NCH];
    float        f0 [NCH][8], f1[NCH][8];

    #pragma unroll
    for (int c = 0; c < NCH; ++c) {
        const int b = blockIdx.x * NCH + c;
        len[c] = lengths[b];
        lm1[c] = len[c] - 1;
        fb [c] = feats + (size_t)b * K_N;
        q  [c] = (lane == START_TAG) ? 1.0f : 0.0f;
        C  [c] = 0.0f;
        #pragma unroll
        for (int i = 0; i < 8; ++i) {
            int r = (i < lm1[c]) ? i : lm1[c];
            f0[c][i] = fb[c][(size_t)r * sT + lane_c];
        }
    }

    #pragma unroll 1
    for (int blk = 0; blk < T_LEN / 16; ++blk) {
        const int t0 = blk * 16;
        // Phase A: prefetch rows t0+8..15 into f1; run steps t0..t0+7 on f0.
        #pragma unroll
        for (int c = 0; c < NCH; ++c)
            #pragma unroll
            for (int i = 0; i < 8; ++i) {
                int r = t0 + 8 + i; r = (r < lm1[c]) ? r : lm1[c];
                f1[c][i] = fb[c][(size_t)r * sT + lane_c];
            }
        #pragma unroll
        for (int i = 0; i < 8; ++i) {
            STEP(0, t0 + i, f0[0][i]);
            STEP(1, t0 + i, f0[1][i]);
        }
        // Phase B: prefetch rows t0+16..23 into f0; run steps t0+8..15 on f1.
        #pragma unroll
        for (int c = 0; c < NCH; ++c)
            #pragma unroll
            for (int i = 0; i < 8; ++i) {
                int r = t0 + 16 + i; r = (r < lm1[c]) ? r : lm1[c];
                f0[c][i] = fb[c][(size_t)r * sT + lane_c];
            }
        #pragma unroll
        for (int i = 0; i < 8; ++i) {
            STEP(0, t0 + 8 + i, f1[0][i]);
            STEP(1, t0 + 8 + i, f1[1][i]);
        }
    }

    // Epilogue per chain: log_z and gold score.
    float result = 0.0f;
    #pragma unroll
    for (int c = 0; c < NCH; ++c) {
        const int b = blockIdx.x * NCH + c;
        float v = (lane < K_N && q[c] > 0.0f)
                ? C[c] + __logf(q[c]) + trans[STOP_TAG * K_N + lane] : -INFINITY;
        float mz = v;
        #pragma unroll
        for (int off = 32; off >= 1; off >>= 1)
            mz = fmaxf(mz, __shfl_xor(mz, off));
        float e = __expf(v - mz);
        float se = e;
        #pragma unroll
        for (int off = 32; off >= 1; off >>= 1)
            se += __shfl_xor(se, off);
        float log_z = mz + __logf(se);

        float gsum = 0.0f;
        for (int t = lane; t < len[c]; t += 64) {
            int next = tags[(size_t)b * T_LEN + t];
            int prev = (t == 0) ? START_TAG : tags[(size_t)b * T_LEN + t - 1];
            gsum += trans[next * K_N + prev]
                  + fb[c][(size_t)t * sT + next];
        }
        #pragma unroll
        for (int off = 32; off >= 1; off >>= 1)
            gsum += __shfl_xor(gsum, off);

        int   last = tags[(size_t)b * T_LEN + len[c] - 1];
        float gold = gsum + trans[STOP_TAG * K_N + last];
        result += log_z - gold;
    }

    if (lane == 0)
        atomicAdd(out, result);
}

extern "C" void kernel_launch(void* const* d_in, const int* in_sizes, int n_in,
                              void* d_out, int out_size, void* d_ws, size_t ws_size,
                              hipStream_t stream) {
    const float* feats   = (const float*)d_in[0];
    const float* trans   = (const float*)d_in[1];
    const int*   tags    = (const int*)d_in[2];
    const int*   lengths = (const int*)d_in[3];
    float* out = (float*)d_out;

    hipMemsetAsync(out, 0, sizeof(float) * out_size, stream);
    crf_fused_kernel<<<B_N / NCH, 64, 0, stream>>>(feats, trans, tags, lengths, out);
}